// Round 5
// baseline (53.115 us; speedup 1.0000x reference)
//
#include <hip/hip_runtime.h>

// MODWT (sym4, level 5, no à-trous upsampling) — outputs h4, h5, lowpass5 as (B,1,3,T).
//
// Circular cross-correlations compose: each output is ONE circular FIR of x.
//   h4[t]  = sum_m F4[m] x[(t+m-16) mod T],  F4 = lo*lo*lo*hi  (29 taps)
//   h5[t]  = sum_m F5[m] x[(t+m-20) mod T],  F5 = lo^4 * hi    (36 taps)
//   lo5[t] = sum_m FL[m] x[(t+m-20) mod T],  FL = lo^5         (36 taps)
//
// Round 5: 8 outputs/thread (window 43 floats -> 11 float4 loads for 8 outputs
// vs 10 for 4), halving per-output VMEM instructions and cutting L1 read
// amplification 40 -> 22 B/output. Shapes hardcoded (T=2^20, B=16) so row/chunk
// decomposition is pure shifts. No LDS, no barriers; nontemporal stores kept
// from R4 (single-variable change for attribution).

typedef float f4v __attribute__((ext_vector_type(4)));

static constexpr float SYM4_LO[8] = {
    -0.07576571478927333f, -0.02963552764599851f, 0.49761866763201545f,
     0.8037387518059161f,   0.29785779560527736f, -0.09921954357684722f,
    -0.012603967262037833f, 0.032223100604071304f};
static constexpr float SYM4_HI[8] = {
    -0.032223100604071304f, -0.012603967262037833f, 0.09921954357684722f,
     0.29785779560527736f,  -0.8037387518059161f,   0.49761866763201545f,
     0.02963552764599851f,  -0.07576571478927333f};

struct FiltPack {
    float f4[36];  // h4 filter padded to window [t-20, t+15] (zeros m<4, m>32)
    float f5[36];
    float fl[36];
};

constexpr FiltPack make_filters() {
    double lo[8], hi[8];
    for (int i = 0; i < 8; ++i) { lo[i] = SYM4_LO[i]; hi[i] = SYM4_HI[i]; }
    double l2[15] = {}, l3[22] = {}, l4[29] = {};
    for (int i = 0; i < 8;  ++i) for (int j = 0; j < 8; ++j) l2[i + j] += lo[i] * lo[j];
    for (int i = 0; i < 15; ++i) for (int j = 0; j < 8; ++j) l3[i + j] += l2[i] * lo[j];
    for (int i = 0; i < 22; ++i) for (int j = 0; j < 8; ++j) l4[i + j] += l3[i] * lo[j];
    double f4[29] = {}, f5[36] = {}, fl[36] = {};
    for (int i = 0; i < 22; ++i) for (int j = 0; j < 8; ++j) f4[i + j] += l3[i] * hi[j];
    for (int i = 0; i < 29; ++i) for (int j = 0; j < 8; ++j) f5[i + j] += l4[i] * hi[j];
    for (int i = 0; i < 29; ++i) for (int j = 0; j < 8; ++j) fl[i + j] += l4[i] * lo[j];
    FiltPack r = {};
    for (int m = 0; m < 36; ++m) {
        r.f4[m] = (m >= 4 && m < 33) ? (float)f4[m - 4] : 0.0f;
        r.f5[m] = (float)f5[m];
        r.fl[m] = (float)fl[m];
    }
    return r;
}
static constexpr FiltPack FP = make_filters();

// Fixed problem shape (reference: B=16, C=1, T=1048576).
constexpr int TT   = 1048576;       // T
constexpr int T4   = TT >> 2;       // float4 chunks per row        = 262144
constexpr int OPR  = TT >> 3;       // 8-output groups per row      = 131072
constexpr int OPR_SHIFT = 17;       // log2(OPR)

__global__ __launch_bounds__(256)
void modwt_direct8_kernel(const float* __restrict__ x, float* __restrict__ out) {
    const int g = blockIdx.x * 256 + threadIdx.x;   // global 8-output group id
    const int b = g >> OPR_SHIFT;                   // batch row
    const int q = g & (OPR - 1);                    // group within row
    const int c = q << 1;                           // first output chunk (f4v)
    // Outputs t0..t0+7, t0 = 4c. Window floats [t0-20, t0+22] -> chunks c-5..c+5.

    const f4v* xr = reinterpret_cast<const f4v*>(x) + (size_t)b * T4;

    float w[44];
    if (c >= 5 && c + 6 <= T4) {
        // Fast path: one base pointer, 11 loads with immediate offsets.
        const f4v* p = xr + (c - 5);
        #pragma unroll
        for (int j = 0; j < 11; ++j)
            reinterpret_cast<f4v*>(w)[j] = p[j];
    } else {
        #pragma unroll
        for (int j = 0; j < 11; ++j) {
            int gc = c - 5 + j;
            if (gc < 0)    gc += T4;
            if (gc >= T4)  gc -= T4;
            reinterpret_cast<f4v*>(w)[j] = xr[gc];
        }
    }

    float a4[8] = {0.f, 0.f, 0.f, 0.f, 0.f, 0.f, 0.f, 0.f};
    float a5[8] = {0.f, 0.f, 0.f, 0.f, 0.f, 0.f, 0.f, 0.f};
    float al[8] = {0.f, 0.f, 0.f, 0.f, 0.f, 0.f, 0.f, 0.f};
    #pragma unroll
    for (int m = 0; m < 36; ++m) {
        const float c4v = FP.f4[m];   // constexpr -> folded; zero taps skipped
        const float c5v = FP.f5[m];
        const float clv = FP.fl[m];
        #pragma unroll
        for (int j = 0; j < 8; ++j) {
            const float xv = w[m + j];
            if (c4v != 0.0f) a4[j] = fmaf(c4v, xv, a4[j]);
            a5[j] = fmaf(c5v, xv, a5[j]);
            al[j] = fmaf(clv, xv, al[j]);
        }
    }

    // out (B,1,3,T): plane s at (b*3+s)*T. Streaming -> nontemporal, no waits.
    f4v* o4 = reinterpret_cast<f4v*>(out);
    const size_t base = ((size_t)b * 3) * T4 + c;
    f4v v;
    v = (f4v){a4[0], a4[1], a4[2], a4[3]}; __builtin_nontemporal_store(v, &o4[base]);
    v = (f4v){a4[4], a4[5], a4[6], a4[7]}; __builtin_nontemporal_store(v, &o4[base + 1]);
    v = (f4v){a5[0], a5[1], a5[2], a5[3]}; __builtin_nontemporal_store(v, &o4[base + T4]);
    v = (f4v){a5[4], a5[5], a5[6], a5[7]}; __builtin_nontemporal_store(v, &o4[base + T4 + 1]);
    v = (f4v){al[0], al[1], al[2], al[3]}; __builtin_nontemporal_store(v, &o4[base + 2 * (size_t)T4]);
    v = (f4v){al[4], al[5], al[6], al[7]}; __builtin_nontemporal_store(v, &o4[base + 2 * (size_t)T4 + 1]);
}

extern "C" void kernel_launch(void* const* d_in, const int* in_sizes, int n_in,
                              void* d_out, int out_size, void* d_ws, size_t ws_size,
                              hipStream_t stream) {
    const float* x = (const float*)d_in[0];
    float* out = (float*)d_out;
    const int B = 16;
    const int totalGroups = B * OPR;           // 2,097,152 8-output groups

    dim3 grid(totalGroups / 256);              // 8192 blocks
    dim3 block(256);
    modwt_direct8_kernel<<<grid, block, 0, stream>>>(x, out);
}

// Round 6
// 50.549 us; speedup vs baseline: 1.0508x; 1.0508x over previous
//
#include <hip/hip_runtime.h>

// MODWT (sym4, level 5, no à-trous upsampling) — outputs h4, h5, lowpass5 as (B,1,3,T).
//
// Circular cross-correlations compose: each output is ONE circular FIR of x.
//   h4[t]  = sum_m F4[m] x[(t+m-16) mod T],  F4 = lo*lo*lo*hi  (29 taps)
//   h5[t]  = sum_m F5[m] x[(t+m-20) mod T],  F5 = lo^4 * hi    (36 taps)
//   lo5[t] = sum_m FL[m] x[(t+m-20) mod T],  FL = lo^5         (36 taps)
//
// Round 6: exact R4 structure (4 outputs/thread, no LDS, no barriers — best
// so far at 51.2 µs), single-variable A/B: nontemporal stores -> PLAIN stores.
// Theory: NT bypasses L2 write-combining; the harness fill hits 7.0 TB/s with
// plain stores through L2, while we plateau at ~5.2 TB/s across 3 structures.
// If this is neutral, the kernel is at the practical mixed-stream HBM ceiling.

typedef float f4v __attribute__((ext_vector_type(4)));

static constexpr float SYM4_LO[8] = {
    -0.07576571478927333f, -0.02963552764599851f, 0.49761866763201545f,
     0.8037387518059161f,   0.29785779560527736f, -0.09921954357684722f,
    -0.012603967262037833f, 0.032223100604071304f};
static constexpr float SYM4_HI[8] = {
    -0.032223100604071304f, -0.012603967262037833f, 0.09921954357684722f,
     0.29785779560527736f,  -0.8037387518059161f,   0.49761866763201545f,
     0.02963552764599851f,  -0.07576571478927333f};

struct FiltPack {
    float f4[36];  // h4 filter padded to window [t-20, t+15] (zeros m<4, m>32)
    float f5[36];
    float fl[36];
};

constexpr FiltPack make_filters() {
    double lo[8], hi[8];
    for (int i = 0; i < 8; ++i) { lo[i] = SYM4_LO[i]; hi[i] = SYM4_HI[i]; }
    double l2[15] = {}, l3[22] = {}, l4[29] = {};
    for (int i = 0; i < 8;  ++i) for (int j = 0; j < 8; ++j) l2[i + j] += lo[i] * lo[j];
    for (int i = 0; i < 15; ++i) for (int j = 0; j < 8; ++j) l3[i + j] += l2[i] * lo[j];
    for (int i = 0; i < 22; ++i) for (int j = 0; j < 8; ++j) l4[i + j] += l3[i] * lo[j];
    double f4[29] = {}, f5[36] = {}, fl[36] = {};
    for (int i = 0; i < 22; ++i) for (int j = 0; j < 8; ++j) f4[i + j] += l3[i] * hi[j];
    for (int i = 0; i < 29; ++i) for (int j = 0; j < 8; ++j) f5[i + j] += l4[i] * hi[j];
    for (int i = 0; i < 29; ++i) for (int j = 0; j < 8; ++j) fl[i + j] += l4[i] * lo[j];
    FiltPack r = {};
    for (int m = 0; m < 36; ++m) {
        r.f4[m] = (m >= 4 && m < 33) ? (float)f4[m - 4] : 0.0f;
        r.f5[m] = (float)f5[m];
        r.fl[m] = (float)fl[m];
    }
    return r;
}
static constexpr FiltPack FP = make_filters();

__global__ __launch_bounds__(256)
void modwt_direct_kernel(const float* __restrict__ x, float* __restrict__ out, int Tn) {
    const int T4 = Tn >> 2;                               // float4 chunks per row
    const int g  = blockIdx.x * 256 + threadIdx.x;        // global output-quad id
    const int b  = g / T4;                                // batch row
    const int c  = g - b * T4;                            // chunk within row
    // Outputs t0..t0+3, t0 = 4c. Window floats [t0-20, t0+19] = chunks c-5..c+4.

    const f4v* xr = reinterpret_cast<const f4v*>(x) + (size_t)b * T4;

    float w[40];
    if (c >= 5 && c + 5 <= T4) {
        // Fast path: one base pointer, 10 loads with immediate offsets.
        const f4v* p = xr + (c - 5);
        #pragma unroll
        for (int j = 0; j < 10; ++j)
            reinterpret_cast<f4v*>(w)[j] = p[j];
    } else {
        #pragma unroll
        for (int j = 0; j < 10; ++j) {
            int gc = c - 5 + j;
            if (gc < 0)    gc += T4;
            if (gc >= T4)  gc -= T4;
            reinterpret_cast<f4v*>(w)[j] = xr[gc];
        }
    }

    float a4[4] = {0.f, 0.f, 0.f, 0.f};
    float a5[4] = {0.f, 0.f, 0.f, 0.f};
    float al[4] = {0.f, 0.f, 0.f, 0.f};
    #pragma unroll
    for (int m = 0; m < 36; ++m) {
        const float c4v = FP.f4[m];   // constexpr -> folded; zero taps skipped
        const float c5v = FP.f5[m];
        const float clv = FP.fl[m];
        #pragma unroll
        for (int j = 0; j < 4; ++j) {
            const float xv = w[m + j];
            if (c4v != 0.0f) a4[j] = fmaf(c4v, xv, a4[j]);
            a5[j] = fmaf(c5v, xv, a5[j]);
            al[j] = fmaf(clv, xv, al[j]);
        }
    }

    // out (B,1,3,T): plane s at (b*3+s)*T. PLAIN stores (L2 write-combining).
    f4v* o4 = reinterpret_cast<f4v*>(out);
    const size_t base = ((size_t)b * 3) * T4 + c;
    o4[base]                  = (f4v){a4[0], a4[1], a4[2], a4[3]};
    o4[base + T4]             = (f4v){a5[0], a5[1], a5[2], a5[3]};
    o4[base + 2 * (size_t)T4] = (f4v){al[0], al[1], al[2], al[3]};
}

extern "C" void kernel_launch(void* const* d_in, const int* in_sizes, int n_in,
                              void* d_out, int out_size, void* d_ws, size_t ws_size,
                              hipStream_t stream) {
    const float* x = (const float*)d_in[0];
    float* out = (float*)d_out;
    const int B  = 16;
    const int Tn = in_sizes[0] / B;            // 1048576
    const int totalQuads = B * (Tn / 4);       // 4,194,304 output-quads

    dim3 grid(totalQuads / 256);               // 16384 blocks
    dim3 block(256);
    modwt_direct_kernel<<<grid, block, 0, stream>>>(x, out, Tn);
}